// Round 1
// baseline (206.467 us; speedup 1.0000x reference)
//
#include <hip/hip_runtime.h>
#include <math.h>

// Problem constants (match reference)
constexpr int BGR = 1024;   // graphs
constexpr int NN  = 128;    // nodes per graph
constexpr int EG  = 2048;   // edges per graph (N*DEG)
constexpr int FIN = 30;
constexpr int H1  = 30;
constexpr int H2  = 50;
constexpr int K1  = 103;    // ceil(0.8*128)
constexpr int K2  = 83;     // ceil(0.8*103)
constexpr int FCW = 100;
constexpr int NT  = 256;    // threads per block

__global__ __launch_bounds__(NT, 2) void gnn_fused(
    const float* __restrict__ x, const int* __restrict__ ei,
    const float* __restrict__ W1, const float* __restrict__ b1, const float* __restrict__ p1,
    const float* __restrict__ W2, const float* __restrict__ b2, const float* __restrict__ p2,
    const float* __restrict__ fc1W, const float* __restrict__ fc1b,
    const float* __restrict__ fc2W, const float* __restrict__ fc2b,
    float* __restrict__ out)
{
  const int g   = blockIdx.x;
  const int tid = threadIdx.x;

  __shared__ float fA[NN*H2];           // 6400 f: conv in / xw / conv out (ping)
  __shared__ float fB[NN*H2];           // 6400 f: (pong)
  __shared__ float sW1[FIN*H1];
  __shared__ float sW2[H1*H2];
  __shared__ float sb1[H1], sp1[H1], sb2[H2], sp2[H2];
  __shared__ short esrc[EG], edst[EG], eord[EG];
  __shared__ int   degc[NN], cstart[NN+1], cur[NN];
  __shared__ float dinv[NN], sc[NN];
  __shared__ short rmap[NN];
  __shared__ float pooled[2*H2], zfc[FCW];

  // ---------------- load graph + weights into LDS ----------------
  for (int i=tid;i<FIN*H1;i+=NT) sW1[i]=W1[i];
  for (int i=tid;i<H1*H2;i+=NT)  sW2[i]=W2[i];
  if (tid<H1){ sb1[tid]=b1[tid]; sp1[tid]=p1[tid]; }
  if (tid<H2){ sb2[tid]=b2[tid]; sp2[tid]=p2[tid]; }
  for (int i=tid;i<NN*FIN;i+=NT) fA[i]=x[(size_t)g*NN*FIN + i];
  {
    const int* srcg = ei + (size_t)g*EG;
    const int* dstg = ei + (size_t)BGR*EG + (size_t)g*EG;
    for (int e=tid;e<EG;e+=NT){
      esrc[e]=(short)(srcg[e] & (NN-1));
      edst[e]=(short)(dstg[e] & (NN-1));
    }
  }
  for (int i=tid;i<NN;i+=NT) degc[i]=0;
  __syncthreads();

  // ---------------- conv1: xw = x @ W1  -> fB ----------------
  for (int t=tid;t<NN*H1;t+=NT){
    int n=t/H1, o=t-n*H1;
    float acc=0.f;
    #pragma unroll
    for (int i=0;i<FIN;i++) acc += fA[n*FIN+i]*sW1[i*H1+o];
    fB[t]=acc;
  }
  for (int e=tid;e<EG;e+=NT) atomicAdd(&degc[edst[e]],1);
  __syncthreads();
  if (tid==0){ int s=0; for (int n=0;n<NN;n++){ cstart[n]=s; s+=degc[n]; } cstart[NN]=s; }
  __syncthreads();
  for (int n=tid;n<NN;n+=NT){ cur[n]=cstart[n]; dinv[n]=1.0f/sqrtf((float)degc[n]+1.0f); }
  __syncthreads();
  for (int e=tid;e<EG;e+=NT){ int p=atomicAdd(&cur[edst[e]],1); eord[p]=esrc[e]; }
  __syncthreads();
  // gather: out = sum_in dinv[s]*dinv[n]*xw[s] + xw[n]/deg + b ; ReLU -> fA
  for (int t=tid;t<NN*H1;t+=NT){
    int n=t/H1, o=t-n*H1;
    float di=dinv[n];
    float rd=1.0f/((float)degc[n]+1.0f);
    float acc=fB[n*H1+o]*rd + sb1[o];
    int e0=cstart[n], e1=cstart[n+1];
    for (int k=e0;k<e1;k++){ int s=eord[k]; acc += di*dinv[s]*fB[s*H1+o]; }
    fA[t]=fmaxf(acc,0.f);
  }
  __syncthreads();

  // ---------------- pool1: score, rank (stable top-k), gate ----------------
  if (tid<NN){
    float nrm=0.f;
    #pragma unroll
    for (int i=0;i<H1;i++) nrm += sp1[i]*sp1[i];
    float d=0.f;
    #pragma unroll
    for (int i=0;i<H1;i++) d += fA[tid*H1+i]*sp1[i];
    sc[tid]=tanhf(d/sqrtf(nrm));
  }
  __syncthreads();
  if (tid<NN){
    float si=sc[tid]; int r=0;
    for (int m=0;m<NN;m++){ float sm=sc[m]; r += (sm>si) || (sm==si && m<tid); }
    rmap[tid] = (r<K1)? (short)r : (short)-1;
  }
  __syncthreads();
  if (tid<NN){
    int r=rmap[tid];
    if (r>=0){
      float gv=sc[tid];
      for (int i=0;i<H1;i++) fB[r*H1+i]=fA[tid*H1+i]*gv;   // gated, rank-ordered
    }
  }
  for (int e=tid;e<EG;e+=NT){                              // remap + mask edges
    short ns=rmap[esrc[e]], nd=rmap[edst[e]];
    if (ns<0 || nd<0){ ns=-1; nd=0; }
    esrc[e]=ns; edst[e]=nd;
  }
  for (int i=tid;i<NN;i+=NT) degc[i]=0;
  __syncthreads();

  // ---------------- conv2 on K1 nodes: xw2 -> fA ----------------
  for (int t=tid;t<K1*H2;t+=NT){
    int n=t/H2, o=t-n*H2;
    float acc=0.f;
    #pragma unroll
    for (int i=0;i<H1;i++) acc += fB[n*H1+i]*sW2[i*H2+o];
    fA[t]=acc;
  }
  for (int e=tid;e<EG;e+=NT) if (esrc[e]>=0) atomicAdd(&degc[edst[e]],1);
  __syncthreads();
  if (tid==0){ int s=0; for (int n=0;n<K1;n++){ cstart[n]=s; s+=degc[n]; } cstart[K1]=s; }
  __syncthreads();
  for (int n=tid;n<K1;n+=NT){ cur[n]=cstart[n]; dinv[n]=1.0f/sqrtf((float)degc[n]+1.0f); }
  __syncthreads();
  for (int e=tid;e<EG;e+=NT) if (esrc[e]>=0){ int p=atomicAdd(&cur[edst[e]],1); eord[p]=esrc[e]; }
  __syncthreads();
  for (int t=tid;t<K1*H2;t+=NT){
    int n=t/H2, o=t-n*H2;
    float di=dinv[n];
    float rd=1.0f/((float)degc[n]+1.0f);
    float acc=fA[n*H2+o]*rd + sb2[o];
    int e0=cstart[n], e1=cstart[n+1];
    for (int k=e0;k<e1;k++){ int s=eord[k]; acc += di*dinv[s]*fA[s*H2+o]; }
    fB[t]=fmaxf(acc,0.f);
  }
  __syncthreads();

  // ---------------- pool2: score + rank ----------------
  if (tid<K1){
    float nrm=0.f;
    #pragma unroll
    for (int i=0;i<H2;i++) nrm += sp2[i]*sp2[i];
    float d=0.f;
    #pragma unroll
    for (int i=0;i<H2;i++) d += fB[tid*H2+i]*sp2[i];
    sc[tid]=tanhf(d/sqrtf(nrm));
  }
  __syncthreads();
  if (tid<K1){
    float si=sc[tid]; int r=0;
    for (int m=0;m<K1;m++){ float sm=sc[m]; r += (sm>si) || (sm==si && m<tid); }
    rmap[tid] = (r<K2)? (short)r : (short)-1;
  }
  __syncthreads();

  // ---------------- global max/mean over kept gated nodes ----------------
  for (int f=tid; f<H2; f+=NT){
    float mx=-INFINITY, sm=0.f;
    for (int n=0;n<K1;n++){
      if (rmap[n]>=0){ float v=fB[n*H2+f]*sc[n]; mx=fmaxf(mx,v); sm+=v; }
    }
    pooled[f]=mx;
    pooled[H2+f]=sm/(float)K2;
  }
  __syncthreads();

  // ---------------- fc1 (100->100, ReLU) ----------------
  if (tid<FCW){
    float acc=fc1b[tid];
    #pragma unroll 4
    for (int i=0;i<2*H2;i++) acc += pooled[i]*fc1W[i*FCW+tid];
    zfc[tid]=fmaxf(acc,0.f);
  }
  __syncthreads();

  // ---------------- fc2 + sigmoid ----------------
  if (tid==0){
    float acc=fc2b[0];
    for (int j=0;j<FCW;j++) acc += zfc[j]*fc2W[j];
    out[g]=1.0f/(1.0f+expf(-acc));
  }
}

extern "C" void kernel_launch(void* const* d_in, const int* in_sizes, int n_in,
                              void* d_out, int out_size, void* d_ws, size_t ws_size,
                              hipStream_t stream) {
  const float* x    = (const float*)d_in[0];
  const int*   ei   = (const int*)d_in[1];
  // d_in[2] = batch (unused; graphs are equal-size, contiguous)
  const float* W1   = (const float*)d_in[3];
  const float* b1   = (const float*)d_in[4];
  const float* p1   = (const float*)d_in[5];
  const float* W2   = (const float*)d_in[6];
  const float* b2   = (const float*)d_in[7];
  const float* p2   = (const float*)d_in[8];
  const float* fc1W = (const float*)d_in[9];
  const float* fc1b = (const float*)d_in[10];
  const float* fc2W = (const float*)d_in[11];
  const float* fc2b = (const float*)d_in[12];
  float* outp = (float*)d_out;

  gnn_fused<<<BGR, NT, 0, stream>>>(x, ei, W1, b1, p1, W2, b2, p2,
                                    fc1W, fc1b, fc2W, fc2b, outp);
}

// Round 2
// 129.579 us; speedup vs baseline: 1.5934x; 1.5934x over previous
//
#include <hip/hip_runtime.h>
#include <math.h>

// Problem constants (match reference)
constexpr int BGR = 1024;   // graphs
constexpr int NN  = 128;    // nodes per graph
constexpr int EG  = 2048;   // edges per graph
constexpr int FIN = 30;
constexpr int H1  = 30;
constexpr int H2  = 50;
constexpr int K1  = 103;    // ceil(0.8*128)
constexpr int K2  = 83;     // ceil(0.8*103)
constexpr int FCW = 100;
constexpr int NT  = 256;    // threads per block
constexpr int EPT = EG/NT;  // 8 edges per thread, kept in registers

// LDS row strides: odd -> lanes reading random rows at same column hit
// distinct banks ((31*s+c)%32 = (c-s)%32 ; (51*s+c)%32 = (19*s+c)%32).
constexpr int S1  = 31;     // stride for 30-wide feature rows
constexpr int S2  = 51;     // stride for 50-wide feature rows
constexpr int FSZ = K1*S2;  // 5253 floats = max(128*31, 103*51)

__global__ __launch_bounds__(NT, 3) void gnn_fused(
    const float* __restrict__ x, const int* __restrict__ ei,
    const float* __restrict__ W1, const float* __restrict__ b1, const float* __restrict__ p1,
    const float* __restrict__ W2, const float* __restrict__ b2, const float* __restrict__ p2,
    const float* __restrict__ fc1W, const float* __restrict__ fc1b,
    const float* __restrict__ fc2W, const float* __restrict__ fc2b,
    float* __restrict__ out)
{
  const int g   = blockIdx.x;
  const int tid = threadIdx.x;

  __shared__ float fA[FSZ];        // x / conv1-out / xw2        (21012 B)
  __shared__ float fB[FSZ];        // xw1 / pool1-gated / conv2-out
  __shared__ short eord[EG];       // CSR-ordered sources         (4096 B)
  __shared__ int   degc[NN], cstart[NN], cur[NN];
  __shared__ float dinv[NN], sc[NN];
  __shared__ short rmap[NN];
  // total ~48.9 KB -> 3 blocks/CU

  // ---- edge list lives in registers for the whole kernel ----
  int es[EPT], ed[EPT];
  {
    const int* srcg = ei + (size_t)g*EG;
    const int* dstg = ei + (size_t)BGR*EG + (size_t)g*EG;
    #pragma unroll
    for (int j=0;j<EPT;j++){ int e=tid+j*NT; es[j]=srcg[e]&(NN-1); ed[j]=dstg[e]&(NN-1); }
  }

  // ---- stage x (stride S1) ----
  for (int l=tid;l<NN*FIN;l+=NT){ int n=l/FIN, i=l-n*FIN; fA[n*S1+i]=x[(size_t)g*NN*FIN+l]; }
  if (tid<NN) degc[tid]=0;
  __syncthreads();

  // ================= conv1 =================
  // xw1 = x @ W1 -> fB   (W1 broadcast from global, L1-resident)
  for (int t=tid;t<NN*H1;t+=NT){
    int n=t/H1, o=t-n*H1;
    float acc=0.f;
    #pragma unroll
    for (int i=0;i<FIN;i++) acc += fA[n*S1+i]*W1[i*H1+o];
    fB[n*S1+o]=acc;
  }
  #pragma unroll
  for (int j=0;j<EPT;j++) atomicAdd(&degc[ed[j]],1);
  __syncthreads();
  // parallel exclusive scan (broadcast reads)
  if (tid<NN){
    int s=0;
    for (int m=0;m<NN;m++){ int d=degc[m]; s += (m<tid)?d:0; }
    cstart[tid]=s; cur[tid]=s;
    dinv[tid]=1.0f/sqrtf((float)degc[tid]+1.0f);
  }
  __syncthreads();
  #pragma unroll
  for (int j=0;j<EPT;j++){ int p=atomicAdd(&cur[ed[j]],1); eord[p]=(short)es[j]; }
  __syncthreads();
  // gather: 2 threads per node, 15 features each, register accumulators
  {
    int n=tid>>1, h=tid&1, ob=h*15;
    float acc[15];
    #pragma unroll
    for (int j=0;j<15;j++) acc[j]=0.f;
    int e0=cstart[n], e1=cur[n];
    float di=dinv[n];
    for (int k=e0;k<e1;k++){
      int s=eord[k];
      float w=di*dinv[s];
      #pragma unroll
      for (int j=0;j<15;j++) acc[j] += w*fB[s*S1+ob+j];
    }
    float rd=1.0f/((float)(e1-e0)+1.0f);
    #pragma unroll
    for (int j=0;j<15;j++){
      float v=acc[j] + fB[n*S1+ob+j]*rd + b1[ob+j];
      fA[n*S1+ob+j]=fmaxf(v,0.f);
    }
  }
  __syncthreads();

  // ================= pool1 =================
  if (tid<NN){
    float nr=0.f, d=0.f;
    #pragma unroll
    for (int i=0;i<H1;i++){ float pv=p1[i]; nr+=pv*pv; d+=fA[tid*S1+i]*pv; }
    sc[tid]=tanhf(d/sqrtf(nr));
  }
  __syncthreads();
  if (tid<NN){             // stable rank == jax.lax.top_k order
    float si=sc[tid]; int r=0;
    for (int m=0;m<NN;m++){ float sm=sc[m]; r += (sm>si) || (sm==si && m<tid); }
    rmap[tid] = (r<K1)? (short)r : (short)-1;
  }
  __syncthreads();
  // gate + compact (2 threads/node)
  {
    int n=tid>>1, h=tid&1, ob=h*15;
    int r=rmap[n];
    if (r>=0){
      float gv=sc[n];
      #pragma unroll
      for (int j=0;j<15;j++) fB[r*S1+ob+j]=fA[n*S1+ob+j]*gv;
    }
  }
  // remap edges (in registers)
  #pragma unroll
  for (int j=0;j<EPT;j++){
    int ns=rmap[es[j]], nd=rmap[ed[j]];
    if ((ns|nd)<0){ es[j]=-1; ed[j]=0; } else { es[j]=ns; ed[j]=nd; }
  }
  if (tid<NN) degc[tid]=0;
  __syncthreads();

  // ================= conv2 =================
  // xw2 = gated @ W2 -> fA (stride S2)
  for (int t=tid;t<K1*H2;t+=NT){
    int n=t/H2, o=t-n*H2;
    float acc=0.f;
    #pragma unroll
    for (int i=0;i<H1;i++) acc += fB[n*S1+i]*W2[i*H2+o];
    fA[n*S2+o]=acc;
  }
  #pragma unroll
  for (int j=0;j<EPT;j++) if (es[j]>=0) atomicAdd(&degc[ed[j]],1);
  __syncthreads();
  if (tid<K1){
    int s=0;
    for (int m=0;m<K1;m++){ int d=degc[m]; s += (m<tid)?d:0; }
    cstart[tid]=s; cur[tid]=s;
    dinv[tid]=1.0f/sqrtf((float)degc[tid]+1.0f);
  }
  __syncthreads();
  #pragma unroll
  for (int j=0;j<EPT;j++) if (es[j]>=0){ int p=atomicAdd(&cur[ed[j]],1); eord[p]=(short)es[j]; }
  __syncthreads();
  // gather: 2 threads/node, 25 features each
  if (tid < 2*K1){
    int n=tid>>1, h=tid&1, ob=h*25;
    float acc[25];
    #pragma unroll
    for (int j=0;j<25;j++) acc[j]=0.f;
    int e0=cstart[n], e1=cur[n];
    float di=dinv[n];
    for (int k=e0;k<e1;k++){
      int s=eord[k];
      float w=di*dinv[s];
      #pragma unroll
      for (int j=0;j<25;j++) acc[j] += w*fA[s*S2+ob+j];
    }
    float rd=1.0f/((float)(e1-e0)+1.0f);
    #pragma unroll
    for (int j=0;j<25;j++){
      float v=acc[j] + fA[n*S2+ob+j]*rd + b2[ob+j];
      fB[n*S2+ob+j]=fmaxf(v,0.f);
    }
  }
  __syncthreads();

  // ================= pool2 (keep-flag only) =================
  if (tid<K1){
    float nr=0.f, d=0.f;
    #pragma unroll
    for (int i=0;i<H2;i++){ float pv=p2[i]; nr+=pv*pv; d+=fB[tid*S2+i]*pv; }
    sc[tid]=tanhf(d/sqrtf(nr));
  }
  __syncthreads();
  if (tid<K1){
    float si=sc[tid]; int r=0;
    for (int m=0;m<K1;m++){ float sm=sc[m]; r += (sm>si) || (sm==si && m<tid); }
    rmap[tid]=(r<K2)?(short)1:(short)0;
  }
  __syncthreads();

  // ================= global max/mean + MLP =================
  float* pooled = fA;        // fA dead after conv2 gather
  float* zfc    = fA + 2*H2 + 4;
  if (tid<H2){
    float mx=-INFINITY, sm=0.f;
    for (int n=0;n<K1;n++){
      if (rmap[n]){ float v=fB[n*S2+tid]*sc[n]; mx=fmaxf(mx,v); sm+=v; }
    }
    pooled[tid]=mx;
    pooled[H2+tid]=sm*(1.0f/(float)K2);
  }
  __syncthreads();
  if (tid<FCW){
    float acc=fc1b[tid];
    #pragma unroll 4
    for (int i=0;i<2*H2;i++) acc += pooled[i]*fc1W[i*FCW+tid];
    zfc[tid]=fmaxf(acc,0.f);
  }
  __syncthreads();
  if (tid<64){
    float a=0.f;
    for (int j=tid;j<FCW;j+=64) a += zfc[j]*fc2W[j];
    #pragma unroll
    for (int off=32;off;off>>=1) a += __shfl_down(a,off,64);
    if (tid==0){
      float acc=fc2b[0]+a;
      out[g]=1.0f/(1.0f+expf(-acc));
    }
  }
}

extern "C" void kernel_launch(void* const* d_in, const int* in_sizes, int n_in,
                              void* d_out, int out_size, void* d_ws, size_t ws_size,
                              hipStream_t stream) {
  const float* x    = (const float*)d_in[0];
  const int*   ei   = (const int*)d_in[1];
  // d_in[2] = batch (unused; graphs are equal-size, contiguous)
  const float* W1   = (const float*)d_in[3];
  const float* b1   = (const float*)d_in[4];
  const float* p1   = (const float*)d_in[5];
  const float* W2   = (const float*)d_in[6];
  const float* b2   = (const float*)d_in[7];
  const float* p2   = (const float*)d_in[8];
  const float* fc1W = (const float*)d_in[9];
  const float* fc1b = (const float*)d_in[10];
  const float* fc2W = (const float*)d_in[11];
  const float* fc2b = (const float*)d_in[12];
  float* outp = (float*)d_out;

  gnn_fused<<<BGR, NT, 0, stream>>>(x, ei, W1, b1, p1, W2, b2, p2,
                                    fc1W, fc1b, fc2W, fc2b, outp);
}

// Round 3
// 90.610 us; speedup vs baseline: 2.2786x; 1.4301x over previous
//
#include <hip/hip_runtime.h>
#include <math.h>

// Problem constants (match reference)
constexpr int BGR = 1024;   // graphs
constexpr int NN  = 128;    // nodes per graph
constexpr int EG  = 2048;   // edges per graph
constexpr int FIN = 30;
constexpr int H1  = 30;
constexpr int H2  = 50;
constexpr int K1  = 103;    // ceil(0.8*128)
constexpr int K2  = 83;     // ceil(0.8*103)
constexpr int FCW = 100;
constexpr int NT  = 256;
constexpr int EPT = EG/NT;  // 8 edges/thread in registers

// Odd strides -> random-row LDS reads spread across banks
constexpr int S1  = 31;
constexpr int S2  = 51;
constexpr int FA_SZ = K1*S2;   // 5253 f (x / xw2 / gated2)
constexpr int FB_SZ = NN*S1;   // 3968 f (xw1 / gated1 / pooled+zfc)
// LDS total: 21012+15872+2048+512+256+512+128 = 40340 B -> 40 KB -> 4 blocks/CU

__global__ __launch_bounds__(NT, 4) void gnn_fused(
    const float* __restrict__ x, const int* __restrict__ ei,
    const float* __restrict__ W1, const float* __restrict__ b1, const float* __restrict__ p1,
    const float* __restrict__ W2, const float* __restrict__ b2, const float* __restrict__ p2,
    const float* __restrict__ fc1W, const float* __restrict__ fc1b,
    const float* __restrict__ fc2W, const float* __restrict__ fc2b,
    float* __restrict__ out)
{
  const int g = blockIdx.x, tid = threadIdx.x;

  __shared__ float fA[FA_SZ];
  __shared__ float fB[FB_SZ];
  __shared__ unsigned char eord[EG];   // CSR-ordered source ids (<128 fit u8)
  __shared__ int   cur[NN];            // atomic counter / scatter cursor / CSR end
  __shared__ short cstart[NN];         // CSR start
  __shared__ float dsc[NN];            // dinv then score (phases alternate)
  __shared__ signed char rmap[NN];     // rank or -1

  // ---- edge list in registers for the whole kernel ----
  int es[EPT], ed[EPT];
  {
    const int* srcg = ei + (size_t)g*EG;
    const int* dstg = ei + (size_t)BGR*EG + (size_t)g*EG;
    #pragma unroll
    for (int j=0;j<EPT;j++){ int e=tid+j*NT; es[j]=srcg[e]&(NN-1); ed[j]=dstg[e]&(NN-1); }
  }
  for (int l=tid;l<NN*FIN;l+=NT){ int n=l/FIN, i=l-n*FIN; fA[n*S1+i]=x[(size_t)g*NN*FIN+l]; }
  if (tid<NN) cur[tid]=0;
  __syncthreads();

  // ================= conv1: xw1 = x@W1 -> fB ; degree count =================
  for (int t=tid;t<NN*H1;t+=NT){
    int n=t/H1, o=t-n*H1;
    float acc=0.f;
    #pragma unroll
    for (int i=0;i<FIN;i++) acc += fA[n*S1+i]*W1[i*H1+o];
    fB[n*S1+o]=acc;
  }
  #pragma unroll
  for (int j=0;j<EPT;j++) atomicAdd(&cur[ed[j]],1);
  __syncthreads();
  // two-phase scan (cur doubles as counter then cursor)
  {
    int myst=0, mydeg=0;
    if (tid<NN){
      for (int m=0;m<NN;m++){ int d=cur[m]; myst += (m<tid)?d:0; }
      mydeg=cur[tid];
    }
    __syncthreads();
    if (tid<NN){ cur[tid]=myst; cstart[tid]=(short)myst; dsc[tid]=1.0f/sqrtf((float)mydeg+1.0f); }
  }
  __syncthreads();
  #pragma unroll
  for (int j=0;j<EPT;j++){ int p=atomicAdd(&cur[ed[j]],1); eord[p]=(unsigned char)es[j]; }
  __syncthreads();

  // conv1 gather -> registers (2 threads/node, 15 feats each)
  float hacc[15];
  const int n1=tid>>1, ob1=(tid&1)*15;
  {
    #pragma unroll
    for (int j=0;j<15;j++) hacc[j]=0.f;
    int e0=cstart[n1], e1=cur[n1];
    float di=dsc[n1];
    for (int k=e0;k<e1;k++){
      int s=eord[k];
      float w=di*dsc[s];
      #pragma unroll
      for (int j=0;j<15;j++) hacc[j]+=w*fB[s*S1+ob1+j];
    }
    float rd=1.0f/((float)(e1-e0)+1.0f);
    #pragma unroll
    for (int j=0;j<15;j++) hacc[j]=fmaxf(hacc[j]+fB[n1*S1+ob1+j]*rd+b1[ob1+j],0.f);
  }

  // ================= pool1 score (exact sequential dot on even lane) =========
  {
    float nr=0.f;
    #pragma unroll
    for (int i=0;i<H1;i++){ float pv=p1[i]; nr+=pv*pv; }
    float oth[15];
    #pragma unroll
    for (int j=0;j<15;j++) oth[j]=__shfl_xor(hacc[j],1,64);
    float d=0.f;
    #pragma unroll
    for (int j=0;j<15;j++) d += hacc[j]*p1[j];       // even lane: i=0..14
    #pragma unroll
    for (int j=0;j<15;j++) d += oth[j]*p1[15+j];     // even lane: i=15..29
    float scv = tanhf(d/sqrtf(nr));
    __syncthreads();                                  // dinv reads done
    if (!(tid&1)) dsc[n1]=scv;
  }
  __syncthreads();
  if (tid<NN){   // stable rank == jax.lax.top_k order
    float si=dsc[tid]; int r=0;
    for (int m=0;m<NN;m++){ float sm=dsc[m]; r += (sm>si)||(sm==si&&m<tid); }
    rmap[tid]=(r<K1)?(signed char)r:(signed char)-1;
  }
  __syncthreads();
  // gated compact write -> fB rows by rank ; remap edges ; reset counters
  {
    int r=rmap[n1];
    if (r>=0){
      float gv=dsc[n1];
      #pragma unroll
      for (int j=0;j<15;j++) fB[r*S1+ob1+j]=hacc[j]*gv;
    }
  }
  #pragma unroll
  for (int j=0;j<EPT;j++){
    int ns=rmap[es[j]], nd=rmap[ed[j]];
    if ((ns|nd)<0){ es[j]=-1; ed[j]=0; } else { es[j]=ns; ed[j]=nd; }
  }
  if (tid<K1) cur[tid]=0;
  __syncthreads();

  // ================= conv2: xw2 = gated@W2 -> fA ; degree count =============
  for (int t=tid;t<K1*H2;t+=NT){
    int n=t/H2, o=t-n*H2;
    float acc=0.f;
    #pragma unroll
    for (int i=0;i<H1;i++) acc += fB[n*S1+i]*W2[i*H2+o];
    fA[n*S2+o]=acc;
  }
  #pragma unroll
  for (int j=0;j<EPT;j++) if (es[j]>=0) atomicAdd(&cur[ed[j]],1);
  __syncthreads();
  {
    int myst=0, mydeg=0;
    if (tid<K1){
      for (int m=0;m<K1;m++){ int d=cur[m]; myst += (m<tid)?d:0; }
      mydeg=cur[tid];
    }
    __syncthreads();
    if (tid<K1){ cur[tid]=myst; cstart[tid]=(short)myst; dsc[tid]=1.0f/sqrtf((float)mydeg+1.0f); }
  }
  __syncthreads();
  #pragma unroll
  for (int j=0;j<EPT;j++) if (es[j]>=0){ int p=atomicAdd(&cur[ed[j]],1); eord[p]=(unsigned char)es[j]; }
  __syncthreads();

  // conv2 gather -> registers (2 threads/node, 25 feats each)
  float oacc[25];
  const int n2=tid>>1, ob2=(tid&1)*25;
  #pragma unroll
  for (int j=0;j<25;j++) oacc[j]=0.f;
  if (tid<2*K1){
    int e0=cstart[n2], e1=cur[n2];
    float di=dsc[n2];
    for (int k=e0;k<e1;k++){
      int s=eord[k];
      float w=di*dsc[s];
      #pragma unroll
      for (int j=0;j<25;j++) oacc[j]+=w*fA[s*S2+ob2+j];
    }
    float rd=1.0f/((float)(e1-e0)+1.0f);
    #pragma unroll
    for (int j=0;j<25;j++) oacc[j]=fmaxf(oacc[j]+fA[n2*S2+ob2+j]*rd+b2[ob2+j],0.f);
  }

  // ================= pool2 score =================
  {
    float nr=0.f;
    #pragma unroll
    for (int i=0;i<H2;i++){ float pv=p2[i]; nr+=pv*pv; }
    float oth[25];
    #pragma unroll
    for (int j=0;j<25;j++) oth[j]=__shfl_xor(oacc[j],1,64);
    float d=0.f;
    #pragma unroll
    for (int j=0;j<25;j++) d += oacc[j]*p2[j];
    #pragma unroll
    for (int j=0;j<25;j++) d += oth[j]*p2[25+j];
    float scv = tanhf(d/sqrtf(nr));
    __syncthreads();                                  // dinv2 reads done
    if (tid<2*K1 && !(tid&1)) dsc[n2]=scv;
  }
  __syncthreads();
  if (tid<K1){
    float si=dsc[tid]; int r=0;
    for (int m=0;m<K1;m++){ float sm=dsc[m]; r += (sm>si)||(sm==si&&m<tid); }
    rmap[tid]=(r<K2)?(signed char)r:(signed char)-1;
  }
  __syncthreads();
  // gated2 compact -> fA rows by rank (xw2 dead)
  if (tid<2*K1){
    int r=rmap[n2];
    if (r>=0){
      float gv=dsc[n2];
      #pragma unroll
      for (int j=0;j<25;j++) fA[r*S2+ob2+j]=oacc[j]*gv;
    }
  }
  __syncthreads();

  // ================= global max/mean + MLP (fB dead -> scratch) =============
  float* pooled = fB;
  float* zfc    = fB + 128;
  if (tid<H2){
    float mx=-INFINITY, sm=0.f;
    for (int n=0;n<K2;n++){ float v=fA[n*S2+tid]; mx=fmaxf(mx,v); sm+=v; }
    pooled[tid]=mx;
    pooled[H2+tid]=sm*(1.0f/(float)K2);
  }
  __syncthreads();
  if (tid<FCW){
    float acc=fc1b[tid];
    #pragma unroll 4
    for (int i=0;i<2*H2;i++) acc += pooled[i]*fc1W[i*FCW+tid];
    zfc[tid]=fmaxf(acc,0.f);
  }
  __syncthreads();
  if (tid<64){
    float a=0.f;
    for (int j=tid;j<FCW;j+=64) a += zfc[j]*fc2W[j];
    #pragma unroll
    for (int off=32;off;off>>=1) a += __shfl_down(a,off,64);
    if (tid==0){
      float acc=fc2b[0]+a;
      out[g]=1.0f/(1.0f+expf(-acc));
    }
  }
}

extern "C" void kernel_launch(void* const* d_in, const int* in_sizes, int n_in,
                              void* d_out, int out_size, void* d_ws, size_t ws_size,
                              hipStream_t stream) {
  const float* x    = (const float*)d_in[0];
  const int*   ei   = (const int*)d_in[1];
  // d_in[2] = batch (unused; graphs are equal-size, contiguous)
  const float* W1   = (const float*)d_in[3];
  const float* b1   = (const float*)d_in[4];
  const float* p1   = (const float*)d_in[5];
  const float* W2   = (const float*)d_in[6];
  const float* b2   = (const float*)d_in[7];
  const float* p2   = (const float*)d_in[8];
  const float* fc1W = (const float*)d_in[9];
  const float* fc1b = (const float*)d_in[10];
  const float* fc2W = (const float*)d_in[11];
  const float* fc2b = (const float*)d_in[12];
  float* outp = (float*)d_out;

  gnn_fused<<<BGR, NT, 0, stream>>>(x, ei, W1, b1, p1, W2, b2, p2,
                                    fc1W, fc1b, fc2W, fc2b, outp);
}

// Round 4
// 70.047 us; speedup vs baseline: 2.9476x; 1.2936x over previous
//
#include <hip/hip_runtime.h>
#include <math.h>

// Problem constants (match reference)
constexpr int BGR = 1024;   // graphs
constexpr int NN  = 128;    // nodes per graph
constexpr int EG  = 2048;   // edges per graph
constexpr int FIN = 30;
constexpr int H1  = 30;
constexpr int H2  = 50;
constexpr int K1  = 103;    // ceil(0.8*128)
constexpr int K2  = 83;     // ceil(0.8*103)
constexpr int FCW = 100;
constexpr int NT  = 256;
constexpr int EPT = EG/NT;  // 8 edges/thread in registers

// XB: node-feature buffer, 32 floats/row, chunk-rotated swizzle:
//   feature i of row s lives at dword  s*32 + (((i>>2)+s)&7)*4 + (i&3)
//   -> per-edge read = 4 aligned ds_read_b128, rows spread over 8 bank groups.
// AGG: aggregated rows, stride 36 floats (144B, 16B-aligned, odd bank-group step).
constexpr int SA   = 36;
constexpr int XBSZ = NN*32;        // 4096 f = 16384 B
constexpr int AGSZ = NN*SA;        // 4608 f = 18432 B
// AGG tail scratch (rows >=104 unused: dword 3744..4607)
constexpr int PMAXo = 3744;        // 4*50
constexpr int PSUMo = 3944;        // 4*50
constexpr int POOLo = 4144;        // 100
constexpr int ZFCo  = 4244;        // 100

__global__ __launch_bounds__(NT, 4) void gnn_fused(
    const float* __restrict__ x, const int* __restrict__ ei,
    const float* __restrict__ W1, const float* __restrict__ b1, const float* __restrict__ p1,
    const float* __restrict__ W2, const float* __restrict__ b2, const float* __restrict__ p2,
    const float* __restrict__ fc1W, const float* __restrict__ fc1b,
    const float* __restrict__ fc2W, const float* __restrict__ fc2b,
    float* __restrict__ out)
{
  const int g = blockIdx.x, tid = threadIdx.x;

  __shared__ float XB[XBSZ];          // x -> W1t -> h1-gated -> W2t
  __shared__ float AGG[AGSZ];         // agg1 -> agg2 (+ tail scratch)
  __shared__ unsigned char eord[EG];
  __shared__ int   cur[NN];
  __shared__ short cstart[NN];
  __shared__ float dsc[NN];           // dinv <-> score (alternating, barrier-guarded)
  __shared__ signed char rmap[NN];

  // ---- edge list in registers for the whole kernel ----
  int es[EPT], ed[EPT];
  {
    const int* srcg = ei + (size_t)g*EG;
    const int* dstg = ei + (size_t)BGR*EG + (size_t)g*EG;
    #pragma unroll
    for (int j=0;j<EPT;j++){ int e=tid+j*NT; es[j]=srcg[e]&(NN-1); ed[j]=dstg[e]&(NN-1); }
  }
  // ---- stage x into swizzled XB ----
  for (int l=tid; l<NN*FIN; l+=NT){
    int n=l/FIN, i=l-n*FIN;
    XB[(n<<5) + ((((i>>2)+n)&7)<<2) + (i&3)] = x[(size_t)g*NN*FIN + l];
  }
  if (tid<NN) cur[tid]=0;
  __syncthreads();

  // ================= CSR build 1 =================
  #pragma unroll
  for (int j=0;j<EPT;j++) atomicAdd(&cur[ed[j]],1);
  __syncthreads();
  {
    int myst=0, mydeg=0;
    if (tid<NN){
      for (int m=0;m<NN;m++){ int d=cur[m]; myst += (m<tid)?d:0; }
      mydeg=cur[tid];
    }
    __syncthreads();
    if (tid<NN){ cur[tid]=myst; cstart[tid]=(short)myst; dsc[tid]=1.0f/sqrtf((float)mydeg+1.0f); }
  }
  __syncthreads();
  #pragma unroll
  for (int j=0;j<EPT;j++){ int p=atomicAdd(&cur[ed[j]],1); eord[p]=(unsigned char)es[j]; }
  __syncthreads();

  const int nA = tid>>1, hf = tid&1;   // node / half split (all 256 valid for conv1)

  // ================= gather1: agg1 = A~ * x  (swizzled b128 reads) ============
  {
    float4 ac0={0,0,0,0},ac1={0,0,0,0},ac2={0,0,0,0},ac3={0,0,0,0};
    const int cq = hf<<2;
    int e0=cstart[nA], e1=cur[nA];
    float di=dsc[nA];
    for (int k=e0;k<e1;k++){
      int s=eord[k];
      float w=di*dsc[s];
      int base=s<<5, rot=s&7;
      float4 v0=*(const float4*)&XB[base+(((cq  +rot)&7)<<2)];
      float4 v1=*(const float4*)&XB[base+(((cq+1+rot)&7)<<2)];
      float4 v2=*(const float4*)&XB[base+(((cq+2+rot)&7)<<2)];
      float4 v3=*(const float4*)&XB[base+(((cq+3+rot)&7)<<2)];
      ac0.x=fmaf(w,v0.x,ac0.x); ac0.y=fmaf(w,v0.y,ac0.y); ac0.z=fmaf(w,v0.z,ac0.z); ac0.w=fmaf(w,v0.w,ac0.w);
      ac1.x=fmaf(w,v1.x,ac1.x); ac1.y=fmaf(w,v1.y,ac1.y); ac1.z=fmaf(w,v1.z,ac1.z); ac1.w=fmaf(w,v1.w,ac1.w);
      ac2.x=fmaf(w,v2.x,ac2.x); ac2.y=fmaf(w,v2.y,ac2.y); ac2.z=fmaf(w,v2.z,ac2.z); ac2.w=fmaf(w,v2.w,ac2.w);
      ac3.x=fmaf(w,v3.x,ac3.x); ac3.y=fmaf(w,v3.y,ac3.y); ac3.z=fmaf(w,v3.z,ac3.z); ac3.w=fmaf(w,v3.w,ac3.w);
    }
    { // self loop: weight 1/(deg+1)
      float w=1.0f/((float)(e1-e0)+1.0f);
      int base=nA<<5, rot=nA&7;
      float4 v0=*(const float4*)&XB[base+(((cq  +rot)&7)<<2)];
      float4 v1=*(const float4*)&XB[base+(((cq+1+rot)&7)<<2)];
      float4 v2=*(const float4*)&XB[base+(((cq+2+rot)&7)<<2)];
      float4 v3=*(const float4*)&XB[base+(((cq+3+rot)&7)<<2)];
      ac0.x=fmaf(w,v0.x,ac0.x); ac0.y=fmaf(w,v0.y,ac0.y); ac0.z=fmaf(w,v0.z,ac0.z); ac0.w=fmaf(w,v0.w,ac0.w);
      ac1.x=fmaf(w,v1.x,ac1.x); ac1.y=fmaf(w,v1.y,ac1.y); ac1.z=fmaf(w,v1.z,ac1.z); ac1.w=fmaf(w,v1.w,ac1.w);
      ac2.x=fmaf(w,v2.x,ac2.x); ac2.y=fmaf(w,v2.y,ac2.y); ac2.z=fmaf(w,v2.z,ac2.z); ac2.w=fmaf(w,v2.w,ac2.w);
      ac3.x=fmaf(w,v3.x,ac3.x); ac3.y=fmaf(w,v3.y,ac3.y); ac3.z=fmaf(w,v3.z,ac3.z); ac3.w=fmaf(w,v3.w,ac3.w);
    }
    float* dp=&AGG[nA*SA + (hf<<4)];    // half0 -> feats 0..15, half1 -> 16..29
    ((float4*)dp)[0]=ac0; ((float4*)dp)[1]=ac1; ((float4*)dp)[2]=ac2;
    if (!hf) ((float4*)dp)[3]=ac3;
    else     *(float2*)(dp+12) = make_float2(ac3.x,ac3.y);
  }
  __syncthreads();                       // x dead; agg1 ready

  // ---- load W1^T (stride 36) into XB[0:1080] ----
  for (int l=tid;l<FIN*H1;l+=NT){ int i=l/H1, o=l-i*H1; XB[o*SA+i]=W1[l]; }
  __syncthreads();

  // ================= mm1: h = relu(agg1 @ W1 + b1) -> regs ===================
  float h[15];
  {
    const float* arow=&AGG[nA*SA];
    float4 a0=((const float4*)arow)[0],a1=((const float4*)arow)[1],a2=((const float4*)arow)[2],
           a3=((const float4*)arow)[3],a4=((const float4*)arow)[4],a5=((const float4*)arow)[5],
           a6=((const float4*)arow)[6];
    float2 a7=*(const float2*)(arow+28);
    const int ob=hf*15;
    #pragma unroll
    for (int jo=0;jo<15;jo++){
      const float* wr=&XB[(ob+jo)*SA];
      float4 w0=((const float4*)wr)[0],w1=((const float4*)wr)[1],w2=((const float4*)wr)[2],
             w3=((const float4*)wr)[3],w4=((const float4*)wr)[4],w5=((const float4*)wr)[5],
             w6=((const float4*)wr)[6];
      float2 w7=*(const float2*)(wr+28);
      float s = a0.x*w0.x+a0.y*w0.y+a0.z*w0.z+a0.w*w0.w
              + a1.x*w1.x+a1.y*w1.y+a1.z*w1.z+a1.w*w1.w
              + a2.x*w2.x+a2.y*w2.y+a2.z*w2.z+a2.w*w2.w
              + a3.x*w3.x+a3.y*w3.y+a3.z*w3.z+a3.w*w3.w
              + a4.x*w4.x+a4.y*w4.y+a4.z*w4.z+a4.w*w4.w
              + a5.x*w5.x+a5.y*w5.y+a5.z*w5.z+a5.w*w5.w
              + a6.x*w6.x+a6.y*w6.y+a6.z*w6.z+a6.w*w6.w
              + a7.x*w7.x+a7.y*w7.y;
      h[jo]=fmaxf(s+b1[ob+jo],0.f);
    }
  }

  // ================= pool1: score, stable rank, gate+compact =================
  {
    float nr=0.f;
    #pragma unroll
    for (int i=0;i<H1;i++){ float pv=p1[i]; nr+=pv*pv; }
    float oth[15];
    #pragma unroll
    for (int j=0;j<15;j++) oth[j]=__shfl_xor(h[j],1,64);
    float d=0.f;
    #pragma unroll
    for (int j=0;j<15;j++) d += h[j]*p1[j];
    #pragma unroll
    for (int j=0;j<15;j++) d += oth[j]*p1[15+j];
    float scv = tanhf(d/sqrtf(nr));
    __syncthreads();                 // all dinv1 / W1t reads complete
    if (!hf) dsc[nA]=scv;
  }
  __syncthreads();
  if (tid<NN){                       // stable rank == jax.lax.top_k order
    float si=dsc[tid]; int r=0;
    for (int m=0;m<NN;m++){ float sm=dsc[m]; r += (sm>si)||(sm==si&&m<tid); }
    rmap[tid]=(r<K1)?(signed char)r:(signed char)-1;
  }
  __syncthreads();
  {  // gated compact -> swizzled XB rows by rank (W1t region dead)
    int r=rmap[nA];
    if (r>=0){
      float gv=dsc[nA];
      const int ob=hf*15;
      #pragma unroll
      for (int j=0;j<15;j++){
        int i=ob+j;
        XB[(r<<5) + ((((i>>2)+r)&7)<<2) + (i&3)] = h[j]*gv;
      }
    }
  }
  #pragma unroll
  for (int j=0;j<EPT;j++){
    int ns=rmap[es[j]], nd=rmap[ed[j]];
    if ((ns|nd)<0){ es[j]=-1; ed[j]=0; } else { es[j]=ns; ed[j]=nd; }
  }
  if (tid<K1) cur[tid]=0;
  __syncthreads();

  // ================= CSR build 2 =================
  #pragma unroll
  for (int j=0;j<EPT;j++) if (es[j]>=0) atomicAdd(&cur[ed[j]],1);
  __syncthreads();
  {
    int myst=0, mydeg=0;
    if (tid<K1){
      for (int m=0;m<K1;m++){ int d=cur[m]; myst += (m<tid)?d:0; }
      mydeg=cur[tid];
    }
    __syncthreads();
    if (tid<K1){ cur[tid]=myst; cstart[tid]=(short)myst; dsc[tid]=1.0f/sqrtf((float)mydeg+1.0f); }
  }
  __syncthreads();
  #pragma unroll
  for (int j=0;j<EPT;j++) if (es[j]>=0){ int p=atomicAdd(&cur[ed[j]],1); eord[p]=(unsigned char)es[j]; }
  __syncthreads();

  // ================= gather2: agg2 = A2~ * h1g (30 feats) ====================
  if (tid<2*K1){
    float4 ac0={0,0,0,0},ac1={0,0,0,0},ac2={0,0,0,0},ac3={0,0,0,0};
    const int cq = hf<<2;
    int e0=cstart[nA], e1=cur[nA];
    float di=dsc[nA];
    for (int k=e0;k<e1;k++){
      int s=eord[k];
      float w=di*dsc[s];
      int base=s<<5, rot=s&7;
      float4 v0=*(const float4*)&XB[base+(((cq  +rot)&7)<<2)];
      float4 v1=*(const float4*)&XB[base+(((cq+1+rot)&7)<<2)];
      float4 v2=*(const float4*)&XB[base+(((cq+2+rot)&7)<<2)];
      float4 v3=*(const float4*)&XB[base+(((cq+3+rot)&7)<<2)];
      ac0.x=fmaf(w,v0.x,ac0.x); ac0.y=fmaf(w,v0.y,ac0.y); ac0.z=fmaf(w,v0.z,ac0.z); ac0.w=fmaf(w,v0.w,ac0.w);
      ac1.x=fmaf(w,v1.x,ac1.x); ac1.y=fmaf(w,v1.y,ac1.y); ac1.z=fmaf(w,v1.z,ac1.z); ac1.w=fmaf(w,v1.w,ac1.w);
      ac2.x=fmaf(w,v2.x,ac2.x); ac2.y=fmaf(w,v2.y,ac2.y); ac2.z=fmaf(w,v2.z,ac2.z); ac2.w=fmaf(w,v2.w,ac2.w);
      ac3.x=fmaf(w,v3.x,ac3.x); ac3.y=fmaf(w,v3.y,ac3.y); ac3.z=fmaf(w,v3.z,ac3.z); ac3.w=fmaf(w,v3.w,ac3.w);
    }
    {
      float w=1.0f/((float)(e1-e0)+1.0f);
      int base=nA<<5, rot=nA&7;
      float4 v0=*(const float4*)&XB[base+(((cq  +rot)&7)<<2)];
      float4 v1=*(const float4*)&XB[base+(((cq+1+rot)&7)<<2)];
      float4 v2=*(const float4*)&XB[base+(((cq+2+rot)&7)<<2)];
      float4 v3=*(const float4*)&XB[base+(((cq+3+rot)&7)<<2)];
      ac0.x=fmaf(w,v0.x,ac0.x); ac0.y=fmaf(w,v0.y,ac0.y); ac0.z=fmaf(w,v0.z,ac0.z); ac0.w=fmaf(w,v0.w,ac0.w);
      ac1.x=fmaf(w,v1.x,ac1.x); ac1.y=fmaf(w,v1.y,ac1.y); ac1.z=fmaf(w,v1.z,ac1.z); ac1.w=fmaf(w,v1.w,ac1.w);
      ac2.x=fmaf(w,v2.x,ac2.x); ac2.y=fmaf(w,v2.y,ac2.y); ac2.z=fmaf(w,v2.z,ac2.z); ac2.w=fmaf(w,v2.w,ac2.w);
      ac3.x=fmaf(w,v3.x,ac3.x); ac3.y=fmaf(w,v3.y,ac3.y); ac3.z=fmaf(w,v3.z,ac3.z); ac3.w=fmaf(w,v3.w,ac3.w);
    }
    float* dp=&AGG[nA*SA + (hf<<4)];
    ((float4*)dp)[0]=ac0; ((float4*)dp)[1]=ac1; ((float4*)dp)[2]=ac2;
    if (!hf) ((float4*)dp)[3]=ac3;
    else     *(float2*)(dp+12) = make_float2(ac3.x,ac3.y);
  }
  __syncthreads();                       // h1g dead; agg2 ready

  // ---- load W2^T (stride 36) into XB[0:1800] ----
  for (int l=tid;l<H1*H2;l+=NT){ int i=l/H2, o=l-i*H2; XB[o*SA+i]=W2[l]; }
  __syncthreads();

  // ================= mm2: h2 = relu(agg2 @ W2 + b2) -> regs ==================
  float oacc[25];
  if (tid<2*K1){
    const float* arow=&AGG[nA*SA];
    float4 a0=((const float4*)arow)[0],a1=((const float4*)arow)[1],a2=((const float4*)arow)[2],
           a3=((const float4*)arow)[3],a4=((const float4*)arow)[4],a5=((const float4*)arow)[5],
           a6=((const float4*)arow)[6];
    float2 a7=*(const float2*)(arow+28);
    const int ob=hf*25;
    #pragma unroll
    for (int jo=0;jo<25;jo++){
      const float* wr=&XB[(ob+jo)*SA];
      float4 w0=((const float4*)wr)[0],w1=((const float4*)wr)[1],w2=((const float4*)wr)[2],
             w3=((const float4*)wr)[3],w4=((const float4*)wr)[4],w5=((const float4*)wr)[5],
             w6=((const float4*)wr)[6];
      float2 w7=*(const float2*)(wr+28);
      float s = a0.x*w0.x+a0.y*w0.y+a0.z*w0.z+a0.w*w0.w
              + a1.x*w1.x+a1.y*w1.y+a1.z*w1.z+a1.w*w1.w
              + a2.x*w2.x+a2.y*w2.y+a2.z*w2.z+a2.w*w2.w
              + a3.x*w3.x+a3.y*w3.y+a3.z*w3.z+a3.w*w3.w
              + a4.x*w4.x+a4.y*w4.y+a4.z*w4.z+a4.w*w4.w
              + a5.x*w5.x+a5.y*w5.y+a5.z*w5.z+a5.w*w5.w
              + a6.x*w6.x+a6.y*w6.y+a6.z*w6.z+a6.w*w6.w
              + a7.x*w7.x+a7.y*w7.y;
      oacc[jo]=fmaxf(s+b2[ob+jo],0.f);
    }
  }

  // ================= pool2 score + rank =================
  {
    float nr=0.f;
    #pragma unroll
    for (int i=0;i<H2;i++){ float pv=p2[i]; nr+=pv*pv; }
    float oth[25];
    #pragma unroll
    for (int j=0;j<25;j++) oth[j]=__shfl_xor(oacc[j],1,64);
    float d=0.f;
    #pragma unroll
    for (int j=0;j<25;j++) d += oacc[j]*p2[j];
    #pragma unroll
    for (int j=0;j<25;j++) d += oth[j]*p2[25+j];
    float scv = tanhf(d/sqrtf(nr));
    __syncthreads();                 // dinv2 reads done
    if (tid<2*K1 && !hf) dsc[nA]=scv;
  }
  __syncthreads();
  if (tid<K1){
    float si=dsc[tid]; int r=0;
    for (int m=0;m<K1;m++){ float sm=dsc[m]; r += (sm>si)||(sm==si&&m<tid); }
    rmap[tid]=(r<K2)?(signed char)1:(signed char)-1;
  }
  __syncthreads();

  // ================= register-space gated global max/mean ====================
  {
    bool kept = (tid<2*K1) && (rmap[nA]>0);
    float gv  = kept ? dsc[nA] : 0.f;
    float mx[25], sm[25];
    #pragma unroll
    for (int j=0;j<25;j++){
      float v=oacc[j]*gv;
      sm[j]= kept ? v : 0.f;
      mx[j]= kept ? v : -3.4e38f;
    }
    #pragma unroll
    for (int off=2; off<64; off<<=1){
      #pragma unroll
      for (int j=0;j<25;j++){
        mx[j]=fmaxf(mx[j],__shfl_xor(mx[j],off,64));
        sm[j]+=__shfl_xor(sm[j],off,64);
      }
    }
    int lane=tid&63, wv=tid>>6;
    if (lane<2){
      #pragma unroll
      for (int j=0;j<25;j++){
        AGG[PMAXo + wv*50 + lane*25 + j]=mx[j];
        AGG[PSUMo + wv*50 + lane*25 + j]=sm[j];
      }
    }
  }
  __syncthreads();
  if (tid<H2){
    float m=-3.4e38f, s=0.f;
    #pragma unroll
    for (int w=0;w<4;w++){ m=fmaxf(m,AGG[PMAXo+w*50+tid]); s+=AGG[PSUMo+w*50+tid]; }
    AGG[POOLo+tid]=m;
    AGG[POOLo+H2+tid]=s*(1.0f/(float)K2);
  }
  __syncthreads();

  // ================= fc1 + fc2 =================
  if (tid<FCW){
    float acc=fc1b[tid];
    #pragma unroll 4
    for (int i=0;i<2*H2;i++) acc += AGG[POOLo+i]*fc1W[i*FCW+tid];
    AGG[ZFCo+tid]=fmaxf(acc,0.f);
  }
  __syncthreads();
  if (tid<64){
    float a=0.f;
    for (int j=tid;j<FCW;j+=64) a += AGG[ZFCo+j]*fc2W[j];
    #pragma unroll
    for (int off=32;off;off>>=1) a += __shfl_down(a,off,64);
    if (tid==0){
      float acc=fc2b[0]+a;
      out[g]=1.0f/(1.0f+expf(-acc));
    }
  }
}

extern "C" void kernel_launch(void* const* d_in, const int* in_sizes, int n_in,
                              void* d_out, int out_size, void* d_ws, size_t ws_size,
                              hipStream_t stream) {
  const float* x    = (const float*)d_in[0];
  const int*   ei   = (const int*)d_in[1];
  // d_in[2] = batch (unused; graphs are equal-size, contiguous)
  const float* W1   = (const float*)d_in[3];
  const float* b1   = (const float*)d_in[4];
  const float* p1   = (const float*)d_in[5];
  const float* W2   = (const float*)d_in[6];
  const float* b2   = (const float*)d_in[7];
  const float* p2   = (const float*)d_in[8];
  const float* fc1W = (const float*)d_in[9];
  const float* fc1b = (const float*)d_in[10];
  const float* fc2W = (const float*)d_in[11];
  const float* fc2b = (const float*)d_in[12];
  float* outp = (float*)d_out;

  gnn_fused<<<BGR, NT, 0, stream>>>(x, ei, W1, b1, p1, W2, b2, p2,
                                    fc1W, fc1b, fc2W, fc2b, outp);
}